// Round 10
// baseline (150.747 us; speedup 1.0000x reference)
//
#include <hip/hip_runtime.h>

// NumericalBiasModule: out[e] = b2 + W2 · relu(W1 · rel(x[src], x[dst]) + b1)
// rel = [ratio | log_ratio | abs_diff | rel_diff], 128 features.
//
// MFMA formulation (validated r4-r8): 16 edges per wave-tile,
// mfma_f32_16x16x32_bf16. lane = (m=lane&15 edge, q=lane>>4 k-chunk);
// A-frag[j] = feat[m][q*8+j]; C/D: col=lane&15 (hid), row=q*4+reg (edge).
//
// Round-10 (fixes r9's absmax 7072): ONE 128B line per node-side.
// Node record, 4 chunks of 32B (chunk q serves lanes with k-chunk q):
//   xh  bf16[8] (16B)  x truncated to bf16
//   xl8 u8[8]   (8B)   mantissa extension, scale 2^15:
//                      f = x/xh - 1 in [0,2^-7)  (bf16 mantissa = 7 bits!
//                      r9 bug: scaled by 2^16 -> clamped half the range)
//                      x ~= xh*(1 + u*2^-15), rel err 2^-16
//   lu8 u8[8]   (8B)   log(x+eps) uniform-quantized over [log(1e-8), 0]:
//                      step 18.4207/255 = 0.0722, err <= 0.036 (better than
//                      fp8 e4m3's step-2 at |lx|~18; r9's other suspect)
// log block decoded to bf16 and fed through the r6-VALIDATED bf16 WL/±WL
// path (no fp8 mfma). 28 bf16 mfma/tile. Lines per edge: 4 -> 2.

#define DD    32
#define HID   64
#define RELF  128
#define EPSF  1e-8f
#define LXLO  -18.420681f          // log(1e-8)
#define LXSC  13.843137f           // 255 / 18.420681
#define LXIV  0.07223796f          // 18.420681 / 255
#define MSC   3.0517578125e-05f    // 2^-15

typedef short  bf16x8 __attribute__((ext_vector_type(8)));
typedef float  f32x4  __attribute__((ext_vector_type(4)));

union U8 { unsigned u[4]; bf16x8 v; };
union Q  { uint4 v; unsigned u[4]; float f[4]; };

static __device__ __forceinline__ unsigned pk_tr(float lo, float hi) {
    return __builtin_amdgcn_perm(__builtin_bit_cast(unsigned, hi),
                                 __builtin_bit_cast(unsigned, lo), 0x07060302u);
}
static __device__ __forceinline__ unsigned rne_bits(float f) {
    unsigned u = __builtin_bit_cast(unsigned, f);
    return u + 0x7fffu + ((u >> 16) & 1u);
}
static __device__ __forceinline__ unsigned pk_rne(float lo, float hi) {
    return __builtin_amdgcn_perm(rne_bits(hi), rne_bits(lo), 0x07060302u);
}
static __device__ __forceinline__ float hi_f32(float f) {
    return __builtin_bit_cast(float, __builtin_bit_cast(unsigned, f) & 0xffff0000u);
}
static __device__ __forceinline__ float ubyte(unsigned w, int b) {
    return (float)((w >> (8 * b)) & 0xffu);   // folds to v_cvt_f32_ubyteN
}
static __device__ __forceinline__ unsigned q8(float v) {   // round+clamp to [0,255]
    int u = (int)(v + 0.5f);
    return (unsigned)(u > 255 ? 255 : (u < 0 ? 0 : u));
}

// ---- prep: one thread per (node, q) 8-dim chunk ----
__global__ __launch_bounds__(256)
void prep_pack(const float* __restrict__ x, uint4* __restrict__ rec, int nchunk)
{
    int i = blockIdx.x * blockDim.x + threadIdx.x;   // chunk = node*4 + q
    if (i >= nchunk) return;
    const float4* xp = (const float4*)(x + (size_t)i * 8);
    float4 v0 = xp[0], v1 = xp[1];
    float xv[8] = {v0.x, v0.y, v0.z, v0.w, v1.x, v1.y, v1.z, v1.w};

    unsigned xh[4];
    #pragma unroll
    for (int p = 0; p < 4; ++p) xh[p] = pk_tr(xv[2*p], xv[2*p+1]);

    unsigned xl[2] = {0u, 0u}, lu[2] = {0u, 0u};
    #pragma unroll
    for (int e = 0; e < 8; ++e) {
        float a  = xv[e];
        float ah = hi_f32(a);
        float f  = 0.f;
        if (ah > 0.f)
            f = (a * __builtin_amdgcn_rcpf(ah) - 1.f) * 32768.f;   // 2^15
        xl[e >> 2] |= q8(f) << (8 * (e & 3));
        float lxe = __logf(a + EPSF);
        lu[e >> 2] |= q8((lxe - LXLO) * LXSC) << (8 * (e & 3));
    }

    uint4 r0; r0.x = xh[0]; r0.y = xh[1]; r0.z = xh[2]; r0.w = xh[3];
    uint4 r1; r1.x = xl[0]; r1.y = xl[1]; r1.z = lu[0]; r1.w = lu[1];
    rec[2 * i]     = r0;
    rec[2 * i + 1] = r1;
}

// PACK=1: gather packed records (2 lines/edge). PACK=0: raw x + per-edge logf.
template <int PACK>
__global__ __launch_bounds__(256, 2)
void edge_bias_mfma(const float* __restrict__ x,
                    const int*   __restrict__ ei,     // [2, E]
                    const float* __restrict__ W1,     // [64, 128]
                    const float* __restrict__ b1,
                    const float* __restrict__ W2,
                    const float* __restrict__ b2,
                    const uint4* __restrict__ rec,    // [N, 8] packed
                    float* __restrict__ out,
                    int E)
{
    const int lane = threadIdx.x & 63;
    const int wave = (blockIdx.x * blockDim.x + threadIdx.x) >> 6;
    const int nwv  = (gridDim.x * blockDim.x) >> 6;
    const int c = lane & 15;      // edge-in-tile (A) / hid-col (C)
    const int q = lane >> 4;      // k-chunk (A,B) / row-quad (C)

    // ---- B fragments, once per kernel (6 bf16 sets, r6 structure) ----
    bf16x8 W0h[4], W0l[4], WL[4], WLn[4], WAf[4], WDf[4];
    #pragma unroll
    for (int nt = 0; nt < 4; ++nt) {
        const float* wr = W1 + (nt * 16 + c) * RELF + q * 8;
        U8 h, l, tt;
        #pragma unroll
        for (int p = 0; p < 4; ++p) {
            float w0 = wr[2 * p], w1 = wr[2 * p + 1];
            h.u[p] = pk_tr(w0, w1);
            l.u[p] = pk_rne(w0 - hi_f32(w0), w1 - hi_f32(w1));
        }
        W0h[nt] = h.v; W0l[nt] = l.v;
        #pragma unroll
        for (int p = 0; p < 4; ++p)
            tt.u[p] = pk_rne(wr[32 + 2 * p], wr[32 + 2 * p + 1]);
        WL[nt] = tt.v;
        #pragma unroll
        for (int p = 0; p < 4; ++p) tt.u[p] ^= 0x80008000u;   // negate bf16 pair
        WLn[nt] = tt.v;
        #pragma unroll
        for (int p = 0; p < 4; ++p)
            tt.u[p] = pk_rne(wr[64 + 2 * p], wr[64 + 2 * p + 1]);
        WAf[nt] = tt.v;
        #pragma unroll
        for (int p = 0; p < 4; ++p)
            tt.u[p] = pk_rne(wr[96 + 2 * p], wr[96 + 2 * p + 1]);
        WDf[nt] = tt.v;
    }
    float b1v[4], w2v[4];
    #pragma unroll
    for (int nt = 0; nt < 4; ++nt) {
        b1v[nt] = b1[nt * 16 + c];
        w2v[nt] = W2[nt * 16 + c];
    }
    const float b2s = b2[0];

    const int ntiles = (E + 15) >> 4;
    int t = wave;
    if (t >= ntiles) return;

    auto ldidx = [&](int tt_, int& s, int& d) {
        if (tt_ >= ntiles) tt_ = t;
        int em = (tt_ << 4) + c; if (em > E - 1) em = E - 1;
        s = ei[em]; d = ei[E + em];
    };
    auto gather = [&](int s, int d, Q& hi_, Q& mi_, Q& hj_, Q& mj_) {
        if constexpr (PACK) {
            const uint4* pi = rec + (size_t)s * 8 + q * 2;
            const uint4* pj = rec + (size_t)d * 8 + q * 2;
            hi_.v = pi[0]; mi_.v = pi[1];
            hj_.v = pj[0]; mj_.v = pj[1];
        } else {
            const uint4* pi = (const uint4*)(x + (size_t)s * DD + q * 8);
            const uint4* pj = (const uint4*)(x + (size_t)d * DD + q * 8);
            hi_.v = pi[0]; mi_.v = pi[1];
            hj_.v = pj[0]; mj_.v = pj[1];
        }
    };
    // decode one packed side -> 8 fp32 x + bf16 log A-frag
    auto decode = [&](const Q& h, const Q& m, float* xv, bf16x8& lfrag) {
        #pragma unroll
        for (int p = 0; p < 4; ++p) {
            float lo = __builtin_bit_cast(float, h.u[p] << 16);
            float hi = __builtin_bit_cast(float, h.u[p] & 0xffff0000u);
            unsigned xb = (p < 2) ? m.u[0] : m.u[1];
            float m0 = ubyte(xb, (2 * p) & 3);
            float m1 = ubyte(xb, (2 * p + 1) & 3);
            xv[2 * p]     = fmaf(lo * MSC, m0, lo);
            xv[2 * p + 1] = fmaf(hi * MSC, m1, hi);
        }
        U8 L;
        #pragma unroll
        for (int p = 0; p < 4; ++p) {
            unsigned lb = (p < 2) ? m.u[2] : m.u[3];
            float l0 = fmaf(ubyte(lb, (2 * p) & 3),     LXIV, LXLO);
            float l1 = fmaf(ubyte(lb, (2 * p + 1) & 3), LXIV, LXLO);
            L.u[p] = pk_rne(l0, l1);
        }
        lfrag = L.v;
    };

    auto compute = [&](int tc, const Q& hI, const Q& mI, const Q& hJ, const Q& mJ) {
        float xiv[8], xjv[8];
        bf16x8 aLi, aLj;
        if constexpr (PACK) {
            decode(hI, mI, xiv, aLi);
            decode(hJ, mJ, xjv, aLj);
        } else {
            #pragma unroll
            for (int p = 0; p < 4; ++p) { xiv[p] = hI.f[p]; xiv[4 + p] = mI.f[p]; }
            #pragma unroll
            for (int p = 0; p < 4; ++p) { xjv[p] = hJ.f[p]; xjv[4 + p] = mJ.f[p]; }
            U8 ti, tj;
            #pragma unroll
            for (int p = 0; p < 4; ++p) {
                ti.u[p] = pk_rne(__logf(xiv[2*p] + EPSF), __logf(xiv[2*p+1] + EPSF));
                tj.u[p] = pk_rne(__logf(xjv[2*p] + EPSF), __logf(xjv[2*p+1] + EPSF));
            }
            aLi = ti.v; aLj = tj.v;
        }

        U8 R, Rl, Aa, Dd;
        #pragma unroll
        for (int p = 0; p < 4; ++p) {
            float a0 = xiv[2*p], a1 = xiv[2*p+1];
            float c0 = xjv[2*p], c1 = xjv[2*p+1];
            float r0 = a0 * __builtin_amdgcn_rcpf(c0 + EPSF);
            float r1 = a1 * __builtin_amdgcn_rcpf(c1 + EPSF);
            float d0 = fabsf(a0 - c0), d1 = fabsf(a1 - c1);
            float g0 = d0 * __builtin_amdgcn_rcpf(fmaxf(a0, c0) + EPSF);
            float g1 = d1 * __builtin_amdgcn_rcpf(fmaxf(a1, c1) + EPSF);
            R.u[p]  = pk_tr(r0, r1);
            Rl.u[p] = pk_tr(r0 - hi_f32(r0), r1 - hi_f32(r1));
            Aa.u[p] = pk_tr(d0, d1);
            Dd.u[p] = pk_tr(g0, g1);
        }

        f32x4 acc[4];
        #pragma unroll
        for (int nt = 0; nt < 4; ++nt) {
            acc[nt][0] = b1v[nt]; acc[nt][1] = b1v[nt];
            acc[nt][2] = b1v[nt]; acc[nt][3] = b1v[nt];
        }
        #pragma unroll
        for (int nt = 0; nt < 4; ++nt) {
            acc[nt] = __builtin_amdgcn_mfma_f32_16x16x32_bf16(R.v,  W0h[nt], acc[nt], 0, 0, 0);
            acc[nt] = __builtin_amdgcn_mfma_f32_16x16x32_bf16(Rl.v, W0h[nt], acc[nt], 0, 0, 0);
            acc[nt] = __builtin_amdgcn_mfma_f32_16x16x32_bf16(R.v,  W0l[nt], acc[nt], 0, 0, 0);
            acc[nt] = __builtin_amdgcn_mfma_f32_16x16x32_bf16(aLi,  WL[nt],  acc[nt], 0, 0, 0);
            acc[nt] = __builtin_amdgcn_mfma_f32_16x16x32_bf16(aLj,  WLn[nt], acc[nt], 0, 0, 0);
            acc[nt] = __builtin_amdgcn_mfma_f32_16x16x32_bf16(Aa.v, WAf[nt], acc[nt], 0, 0, 0);
            acc[nt] = __builtin_amdgcn_mfma_f32_16x16x32_bf16(Dd.v, WDf[nt], acc[nt], 0, 0, 0);
        }

        float p[4];
        #pragma unroll
        for (int r = 0; r < 4; ++r) {
            float pp = 0.f;
            #pragma unroll
            for (int nt = 0; nt < 4; ++nt)
                pp = fmaf(fmaxf(acc[nt][r], 0.f), w2v[nt], pp);
            pp += __shfl_xor(pp, 1);
            pp += __shfl_xor(pp, 2);
            pp += __shfl_xor(pp, 4);
            pp += __shfl_xor(pp, 8);
            p[r] = pp;
        }
        if (c < 4) {
            const int e = (tc << 4) + q * 4 + c;
            if (e < E) {
                float v = (c == 0) ? p[0] : (c == 1) ? p[1] : (c == 2) ? p[2] : p[3];
                out[e] = v + b2s;
            }
        }
    };

    // ---- depth-1 pipeline: idx 2 ahead, gathers 1 ahead ----
    Q hiC, miC, hjC, mjC;
    int srcN, dstN;
    { int s, d; ldidx(t, s, d); gather(s, d, hiC, miC, hjC, mjC); }
    ldidx(t + nwv, srcN, dstN);

    for (; t < ntiles; t += nwv) {
        Q hiN, miN, hjN, mjN;
        gather(srcN, dstN, hiN, miN, hjN, mjN);       // tile t+nwv
        int srcN2, dstN2;
        ldidx(t + 2 * nwv, srcN2, dstN2);

        compute(t, hiC, miC, hjC, mjC);

        hiC = hiN; miC = miN; hjC = hjN; mjC = mjN;
        srcN = srcN2; dstN = dstN2;
    }
}

extern "C" void kernel_launch(void* const* d_in, const int* in_sizes, int n_in,
                              void* d_out, int out_size, void* d_ws, size_t ws_size,
                              hipStream_t stream)
{
    const float* x   = (const float*)d_in[0];
    const int*   ei  = (const int*)  d_in[1];
    const float* W1  = (const float*)d_in[2];
    const float* b1  = (const float*)d_in[3];
    const float* W2  = (const float*)d_in[4];
    const float* b2  = (const float*)d_in[5];
    float* out = (float*)d_out;

    const int E  = out_size;       // 1,000,000
    const int Nd = in_sizes[0];    // N*D = 3,200,000
    uint4* rec = (uint4*)d_ws;     // N * 128 bytes = Nd * 4 bytes

    const bool pack = ws_size >= (size_t)Nd * 4 && (Nd % 8) == 0;
    if (pack) {
        const int nchunk = Nd / 8;  // (node,q) chunks
        prep_pack<<<(nchunk + 255) / 256, 256, 0, stream>>>(x, rec, nchunk);
        edge_bias_mfma<1><<<1024, 256, 0, stream>>>(x, ei, W1, b1, W2, b2, rec, out, E);
    } else {
        edge_bias_mfma<0><<<1024, 256, 0, stream>>>(x, ei, W1, b1, W2, b2, rec, out, E);
    }
}

// Round 11
// 143.417 us; speedup vs baseline: 1.0511x; 1.0511x over previous
//
#include <hip/hip_runtime.h>

// NumericalBiasModule: out[e] = b2 + W2 · relu(W1 · rel(x[src], x[dst]) + b1)
// rel = [ratio | log_ratio | abs_diff | rel_diff], 128 features.
//
// MFMA formulation (validated r4-r8): 16 edges per wave-tile,
// mfma_f32_16x16x32_bf16. lane = (m=lane&15 edge, q=lane>>4 k-chunk);
// A-frag[j] = feat[m][q*8+j]; C/D: col=lane&15 (hid), row=q*4+reg (edge).
// Math = r6 exactly (absmax 2.0): lx = bf16 log(x+eps) precomputed per node;
// log_ratio via linearity lxi·W + (-lxj)·W; ratio block bf16 hi/lo split.
//
// Round-11 change (r4-r10 forensics: ~200 regs/wave -> 2 waves/SIMD ->
// ~1500 stall cyc/tile/SIMD that no pipeline depth or traffic cut fixed):
//  * 5 weight-fragment sets (WLn folded into an A-side sign flip) live in a
//    20KB per-block LDS image in FRAGMENT order (frag f at f*1KB + lane*16,
//    contiguous per-lane 16B -> conflict-free ds_read_b128), built once per
//    block, read just-in-time per tile (20 ds_read_b128).
//  * asm-opaque lane offset per tile prevents LICM re-hoisting the weights
//    into registers.
//  * __launch_bounds__(256,4): cap 128 VGPRs -> 4 waves/SIMD residency.

#define DD    32
#define HID   64
#define RELF  128
#define EPSF  1e-8f

typedef short  bf16x8 __attribute__((ext_vector_type(8)));
typedef float  f32x4  __attribute__((ext_vector_type(4)));

union U8 { unsigned u[4]; bf16x8 v; uint4 q4; };

static __device__ __forceinline__ unsigned pk_tr(float lo, float hi) {
    return __builtin_amdgcn_perm(__builtin_bit_cast(unsigned, hi),
                                 __builtin_bit_cast(unsigned, lo), 0x07060302u);
}
static __device__ __forceinline__ unsigned rne_bits(float f) {
    unsigned u = __builtin_bit_cast(unsigned, f);
    return u + 0x7fffu + ((u >> 16) & 1u);
}
static __device__ __forceinline__ unsigned pk_rne(float lo, float hi) {
    return __builtin_amdgcn_perm(rne_bits(hi), rne_bits(lo), 0x07060302u);
}
static __device__ __forceinline__ float hi_f32(float f) {
    return __builtin_bit_cast(float, __builtin_bit_cast(unsigned, f) & 0xffff0000u);
}

__global__ __launch_bounds__(256)
void prep_logx(const float* __restrict__ x, unsigned* __restrict__ lx, int nq)
{
    int i = blockIdx.x * blockDim.x + threadIdx.x;
    if (i >= nq) return;
    float4 v = ((const float4*)x)[i];
    uint2 o;
    o.x = pk_rne(__logf(v.x + EPSF), __logf(v.y + EPSF));
    o.y = pk_rne(__logf(v.z + EPSF), __logf(v.w + EPSF));
    ((uint2*)lx)[i] = o;
}

template <int PRE>
__global__ __launch_bounds__(256, 4)
void edge_bias_mfma(const float* __restrict__ x,
                    const int*   __restrict__ ei,     // [2, E]
                    const float* __restrict__ W1,     // [64, 128]
                    const float* __restrict__ b1,
                    const float* __restrict__ W2,
                    const float* __restrict__ b2,
                    const short* __restrict__ lx,     // [N, 32] bf16 log(x+eps)
                    float* __restrict__ out,
                    int E)
{
    const int lane = threadIdx.x & 63;
    const int wv   = threadIdx.x >> 6;
    const int wave = (blockIdx.x * blockDim.x + threadIdx.x) >> 6;
    const int nwv  = (gridDim.x * blockDim.x) >> 6;
    const int c = lane & 15;      // edge-in-tile (A) / hid-col (C)
    const int q = lane >> 4;      // k-chunk (A,B) / row-quad (C)

    // ---- LDS weight image: 5 sets x 4 nt = 20 frags x 1KB ----
    // set 0: W0h (ratio hi)  1: W0l (ratio lo)  2: WL (log)  3: WA  4: WD
    __shared__ uint4 sW[20 * 64];
    for (int s = wv; s < 5; s += 4) {           // wave w builds sets w, w+4
        #pragma unroll
        for (int nt = 0; nt < 4; ++nt) {
            const float* wr = W1 + (nt * 16 + c) * RELF + q * 8;
            U8 t;
            if (s == 0) {
                #pragma unroll
                for (int p = 0; p < 4; ++p)
                    t.u[p] = pk_tr(wr[2*p], wr[2*p+1]);
            } else if (s == 1) {
                #pragma unroll
                for (int p = 0; p < 4; ++p) {
                    float w0 = wr[2*p], w1 = wr[2*p+1];
                    t.u[p] = pk_rne(w0 - hi_f32(w0), w1 - hi_f32(w1));
                }
            } else {
                const int base = (s == 2) ? 32 : (s == 3) ? 64 : 96;
                #pragma unroll
                for (int p = 0; p < 4; ++p)
                    t.u[p] = pk_rne(wr[base + 2*p], wr[base + 2*p + 1]);
            }
            sW[(s * 4 + nt) * 64 + lane] = t.q4;
        }
    }
    __syncthreads();

    float b1v[4], w2v[4];
    #pragma unroll
    for (int nt = 0; nt < 4; ++nt) {
        b1v[nt] = b1[nt * 16 + c];
        w2v[nt] = W2[nt * 16 + c];
    }
    const float b2s = b2[0];

    const int ntiles = (E + 15) >> 4;
    int t = wave;
    if (t >= ntiles) return;   // after the barrier (grid waves << ntiles anyway)

    auto ldidx = [&](int tt_, int& s, int& d) {
        if (tt_ >= ntiles) tt_ = t;
        int em = (tt_ << 4) + c; if (em > E - 1) em = E - 1;
        s = ei[em]; d = ei[E + em];
    };
    auto gather = [&](int s, int d, float4& A0, float4& A1,
                      float4& B0, float4& B1, bf16x8& Li, bf16x8& Lj) {
        const float* pi = x + (long)s * DD + q * 8;
        const float* pj = x + (long)d * DD + q * 8;
        A0 = ((const float4*)pi)[0]; A1 = ((const float4*)pi)[1];
        B0 = ((const float4*)pj)[0]; B1 = ((const float4*)pj)[1];
        if constexpr (PRE) {
            Li = *(const bf16x8*)(lx + (long)s * DD + q * 8);
            Lj = *(const bf16x8*)(lx + (long)d * DD + q * 8);
        } else { (void)Li; (void)Lj; }
    };

    auto compute = [&](int tc, float4 xi0, float4 xi1, float4 xj0, float4 xj1,
                       bf16x8 aLi, bf16x8 aLj) {
        float xiv[8] = {xi0.x, xi0.y, xi0.z, xi0.w, xi1.x, xi1.y, xi1.z, xi1.w};
        float xjv[8] = {xj0.x, xj0.y, xj0.z, xj0.w, xj1.x, xj1.y, xj1.z, xj1.w};

        if constexpr (!PRE) {
            U8 ti, tj;
            #pragma unroll
            for (int p = 0; p < 4; ++p) {
                ti.u[p] = pk_rne(__logf(xiv[2*p] + EPSF), __logf(xiv[2*p+1] + EPSF));
                tj.u[p] = pk_rne(__logf(xjv[2*p] + EPSF), __logf(xjv[2*p+1] + EPSF));
            }
            aLi = ti.v; aLj = tj.v;
        }
        // -lxj: bf16 sign flip on the A side (replaces the WLn weight set)
        U8 nj; nj.v = aLj;
        #pragma unroll
        for (int p = 0; p < 4; ++p) nj.u[p] ^= 0x80008000u;

        U8 R, Rl, Aa, Dd;
        #pragma unroll
        for (int p = 0; p < 4; ++p) {
            float a0 = xiv[2*p], a1 = xiv[2*p+1];
            float c0 = xjv[2*p], c1 = xjv[2*p+1];
            float r0 = a0 * __builtin_amdgcn_rcpf(c0 + EPSF);
            float r1 = a1 * __builtin_amdgcn_rcpf(c1 + EPSF);
            float d0 = fabsf(a0 - c0), d1 = fabsf(a1 - c1);
            float g0 = d0 * __builtin_amdgcn_rcpf(fmaxf(a0, c0) + EPSF);
            float g1 = d1 * __builtin_amdgcn_rcpf(fmaxf(a1, c1) + EPSF);
            R.u[p]  = pk_tr(r0, r1);
            Rl.u[p] = pk_tr(r0 - hi_f32(r0), r1 - hi_f32(r1));
            Aa.u[p] = pk_tr(d0, d1);
            Dd.u[p] = pk_tr(g0, g1);
        }

        // opaque lane offset: stops LICM hoisting the weight ds_reads into
        // loop-carried registers (the r4-r10 occupancy killer)
        int off = lane;
        asm volatile("" : "+v"(off));
        auto ldfrag = [&](int s, int nt) {
            U8 w; w.q4 = sW[(s * 4 + nt) * 64 + off];
            return w.v;
        };

        f32x4 acc[4];
        #pragma unroll
        for (int nt = 0; nt < 4; ++nt) {
            acc[nt][0] = b1v[nt]; acc[nt][1] = b1v[nt];
            acc[nt][2] = b1v[nt]; acc[nt][3] = b1v[nt];
        }
        #pragma unroll
        for (int nt = 0; nt < 4; ++nt) {
            bf16x8 fW0h = ldfrag(0, nt);
            bf16x8 fW0l = ldfrag(1, nt);
            bf16x8 fWL  = ldfrag(2, nt);
            bf16x8 fWA  = ldfrag(3, nt);
            bf16x8 fWD  = ldfrag(4, nt);
            acc[nt] = __builtin_amdgcn_mfma_f32_16x16x32_bf16(R.v,  fW0h, acc[nt], 0, 0, 0);
            acc[nt] = __builtin_amdgcn_mfma_f32_16x16x32_bf16(Rl.v, fW0h, acc[nt], 0, 0, 0);
            acc[nt] = __builtin_amdgcn_mfma_f32_16x16x32_bf16(R.v,  fW0l, acc[nt], 0, 0, 0);
            acc[nt] = __builtin_amdgcn_mfma_f32_16x16x32_bf16(aLi,  fWL,  acc[nt], 0, 0, 0);
            acc[nt] = __builtin_amdgcn_mfma_f32_16x16x32_bf16(nj.v, fWL,  acc[nt], 0, 0, 0);
            acc[nt] = __builtin_amdgcn_mfma_f32_16x16x32_bf16(Aa.v, fWA,  acc[nt], 0, 0, 0);
            acc[nt] = __builtin_amdgcn_mfma_f32_16x16x32_bf16(Dd.v, fWD,  acc[nt], 0, 0, 0);
        }

        float p[4];
        #pragma unroll
        for (int r = 0; r < 4; ++r) {
            float pp = 0.f;
            #pragma unroll
            for (int nt = 0; nt < 4; ++nt)
                pp = fmaf(fmaxf(acc[nt][r], 0.f), w2v[nt], pp);
            pp += __shfl_xor(pp, 1);
            pp += __shfl_xor(pp, 2);
            pp += __shfl_xor(pp, 4);
            pp += __shfl_xor(pp, 8);
            p[r] = pp;
        }
        if (c < 4) {
            const int e = (tc << 4) + q * 4 + c;
            if (e < E) {
                float v = (c == 0) ? p[0] : (c == 1) ? p[1] : (c == 2) ? p[2] : p[3];
                out[e] = v + b2s;
            }
        }
    };

    // ---- depth-1 pipeline: idx 2 ahead, gathers 1 ahead (r6 structure) ----
    float4 xi0C, xi1C, xj0C, xj1C;
    bf16x8 LiC, LjC;
    int srcN, dstN;
    { int s, d; ldidx(t, s, d); gather(s, d, xi0C, xi1C, xj0C, xj1C, LiC, LjC); }
    ldidx(t + nwv, srcN, dstN);

    for (; t < ntiles; t += nwv) {
        float4 xi0N, xi1N, xj0N, xj1N;
        bf16x8 LiN, LjN;
        gather(srcN, dstN, xi0N, xi1N, xj0N, xj1N, LiN, LjN);   // tile t+nwv
        int srcN2, dstN2;
        ldidx(t + 2 * nwv, srcN2, dstN2);

        compute(t, xi0C, xi1C, xj0C, xj1C, LiC, LjC);

        xi0C = xi0N; xi1C = xi1N; xj0C = xj0N; xj1C = xj1N;
        LiC = LiN; LjC = LjN;
        srcN = srcN2; dstN = dstN2;
    }
}

extern "C" void kernel_launch(void* const* d_in, const int* in_sizes, int n_in,
                              void* d_out, int out_size, void* d_ws, size_t ws_size,
                              hipStream_t stream)
{
    const float* x   = (const float*)d_in[0];
    const int*   ei  = (const int*)  d_in[1];
    const float* W1  = (const float*)d_in[2];
    const float* b1  = (const float*)d_in[3];
    const float* W2  = (const float*)d_in[4];
    const float* b2  = (const float*)d_in[5];
    float* out = (float*)d_out;

    const int E  = out_size;       // 1,000,000
    const int Nd = in_sizes[0];    // N*D = 3,200,000
    short* lx = (short*)d_ws;

    const bool pre = ws_size >= (size_t)Nd * sizeof(short) && (Nd % 4) == 0;
    if (pre) {
        const int nq = Nd / 4;
        prep_logx<<<(nq + 255) / 256, 256, 0, stream>>>(x, (unsigned*)lx, nq);
        edge_bias_mfma<1><<<2048, 256, 0, stream>>>(x, ei, W1, b1, W2, b2, lx, out, E);
    } else {
        edge_bias_mfma<0><<<2048, 256, 0, stream>>>(x, ei, W1, b1, W2, b2, lx, out, E);
    }
}

// Round 12
// 136.515 us; speedup vs baseline: 1.1043x; 1.0506x over previous
//
#include <hip/hip_runtime.h>

// NumericalBiasModule: out[e] = b2 + W2 · relu(W1 · rel(x[src], x[dst]) + b1)
// rel = [ratio | log_ratio | abs_diff | rel_diff], 128 features.
//
// MFMA tile (validated r4-r11): 16 edges/wave, mfma_f32_16x16x32_bf16.
// lane = (m=lane&15 edge, q=lane>>4 k-chunk); A-frag[j] = feat[m][q*8+j];
// C/D: col=lane&15 (hid), row=q*4+reg (edge).
//
// Round-12 = r10 traffic fix x r11 residency fix (each alone was neutral):
//  * ONE 128B line per node-side (prep kernel): per q-chunk 32B =
//      xh bf16[8] | xl8 u8[8] (mantissa ext, scale 2^15, rel err 2^-16)
//                 | lu8 u8[8] (log(x+eps) u8-quantized over [log 1e-8, 0])
//    -> 2 gather lines/edge instead of 4. [encodings validated r10, absmax 2.0]
//  * Weights in a 20KB LDS image (5 frag sets; -lxj via A-side sign flip),
//    read just-in-time per tile via asm-opaque offset -> VGPR ~60-90,
//    4 waves/SIMD. [validated r11: occupancy 36%]
// Evidence for the combination: r6/r8/r11 all pin L2-miss fill at ~2.9 TB/s
// regardless of structure (fabric/L3 random-line service wall); r10 cut the
// traffic but lacked the residency to stay latency-covered.

#define DD    32
#define HID   64
#define RELF  128
#define EPSF  1e-8f
#define LXLO  -18.420681f          // log(1e-8)
#define LXSC  13.843137f           // 255 / 18.420681
#define LXIV  0.07223796f          // 18.420681 / 255
#define MSC   3.0517578125e-05f    // 2^-15

typedef short  bf16x8 __attribute__((ext_vector_type(8)));
typedef float  f32x4  __attribute__((ext_vector_type(4)));

union U8 { unsigned u[4]; bf16x8 v; uint4 q4; };
union Q  { uint4 v; unsigned u[4]; float f[4]; };

static __device__ __forceinline__ unsigned pk_tr(float lo, float hi) {
    return __builtin_amdgcn_perm(__builtin_bit_cast(unsigned, hi),
                                 __builtin_bit_cast(unsigned, lo), 0x07060302u);
}
static __device__ __forceinline__ unsigned rne_bits(float f) {
    unsigned u = __builtin_bit_cast(unsigned, f);
    return u + 0x7fffu + ((u >> 16) & 1u);
}
static __device__ __forceinline__ unsigned pk_rne(float lo, float hi) {
    return __builtin_amdgcn_perm(rne_bits(hi), rne_bits(lo), 0x07060302u);
}
static __device__ __forceinline__ float hi_f32(float f) {
    return __builtin_bit_cast(float, __builtin_bit_cast(unsigned, f) & 0xffff0000u);
}
static __device__ __forceinline__ float ubyte(unsigned w, int b) {
    return (float)((w >> (8 * b)) & 0xffu);   // folds to v_cvt_f32_ubyteN
}
static __device__ __forceinline__ unsigned q8(float v) {
    int u = (int)(v + 0.5f);
    return (unsigned)(u > 255 ? 255 : (u < 0 ? 0 : u));
}

// ---- prep: one thread per (node, q) 8-dim chunk ----
__global__ __launch_bounds__(256)
void prep_pack(const float* __restrict__ x, uint4* __restrict__ rec, int nchunk)
{
    int i = blockIdx.x * blockDim.x + threadIdx.x;   // chunk = node*4 + q
    if (i >= nchunk) return;
    const float4* xp = (const float4*)(x + (size_t)i * 8);
    float4 v0 = xp[0], v1 = xp[1];
    float xv[8] = {v0.x, v0.y, v0.z, v0.w, v1.x, v1.y, v1.z, v1.w};

    unsigned xh[4];
    #pragma unroll
    for (int p = 0; p < 4; ++p) xh[p] = pk_tr(xv[2*p], xv[2*p+1]);

    unsigned xl[2] = {0u, 0u}, lu[2] = {0u, 0u};
    #pragma unroll
    for (int e = 0; e < 8; ++e) {
        float a  = xv[e];
        float ah = hi_f32(a);
        float f  = 0.f;
        if (ah > 0.f)
            f = (a * __builtin_amdgcn_rcpf(ah) - 1.f) * 32768.f;   // 2^15
        xl[e >> 2] |= q8(f) << (8 * (e & 3));
        float lxe = __logf(a + EPSF);
        lu[e >> 2] |= q8((lxe - LXLO) * LXSC) << (8 * (e & 3));
    }

    uint4 r0; r0.x = xh[0]; r0.y = xh[1]; r0.z = xh[2]; r0.w = xh[3];
    uint4 r1; r1.x = xl[0]; r1.y = xl[1]; r1.z = lu[0]; r1.w = lu[1];
    rec[2 * i]     = r0;
    rec[2 * i + 1] = r1;
}

// PACK=1: packed records (2 lines/edge). PACK=0: raw x + per-edge logf.
template <int PACK>
__global__ __launch_bounds__(256, 4)
void edge_bias_mfma(const float* __restrict__ x,
                    const int*   __restrict__ ei,     // [2, E]
                    const float* __restrict__ W1,     // [64, 128]
                    const float* __restrict__ b1,
                    const float* __restrict__ W2,
                    const float* __restrict__ b2,
                    const uint4* __restrict__ rec,    // [N, 8] packed
                    float* __restrict__ out,
                    int E)
{
    const int lane = threadIdx.x & 63;
    const int wv   = threadIdx.x >> 6;
    const int wave = (blockIdx.x * blockDim.x + threadIdx.x) >> 6;
    const int nwv  = (gridDim.x * blockDim.x) >> 6;
    const int c = lane & 15;      // edge-in-tile (A) / hid-col (C)
    const int q = lane >> 4;      // k-chunk (A,B) / row-quad (C)

    // ---- LDS weight image: 5 sets x 4 nt = 20 frags x 1KB (r11) ----
    // 0: W0h (ratio hi)  1: W0l (ratio lo)  2: WL (log)  3: WA  4: WD
    __shared__ uint4 sW[20 * 64];
    for (int s = wv; s < 5; s += 4) {
        #pragma unroll
        for (int nt = 0; nt < 4; ++nt) {
            const float* wr = W1 + (nt * 16 + c) * RELF + q * 8;
            U8 t;
            if (s == 0) {
                #pragma unroll
                for (int p = 0; p < 4; ++p)
                    t.u[p] = pk_tr(wr[2*p], wr[2*p+1]);
            } else if (s == 1) {
                #pragma unroll
                for (int p = 0; p < 4; ++p) {
                    float w0 = wr[2*p], w1 = wr[2*p+1];
                    t.u[p] = pk_rne(w0 - hi_f32(w0), w1 - hi_f32(w1));
                }
            } else {
                const int base = (s == 2) ? 32 : (s == 3) ? 64 : 96;
                #pragma unroll
                for (int p = 0; p < 4; ++p)
                    t.u[p] = pk_rne(wr[base + 2*p], wr[base + 2*p + 1]);
            }
            sW[(s * 4 + nt) * 64 + lane] = t.q4;
        }
    }
    __syncthreads();

    float b1v[4], w2v[4];
    #pragma unroll
    for (int nt = 0; nt < 4; ++nt) {
        b1v[nt] = b1[nt * 16 + c];
        w2v[nt] = W2[nt * 16 + c];
    }
    const float b2s = b2[0];

    const int ntiles = (E + 15) >> 4;
    int t = wave;
    if (t >= ntiles) return;

    auto ldidx = [&](int tt_, int& s, int& d) {
        if (tt_ >= ntiles) tt_ = t;
        int em = (tt_ << 4) + c; if (em > E - 1) em = E - 1;
        s = ei[em]; d = ei[E + em];
    };
    auto gather = [&](int s, int d, Q& hi_, Q& mi_, Q& hj_, Q& mj_) {
        if constexpr (PACK) {
            const uint4* pi = rec + (size_t)s * 8 + q * 2;
            const uint4* pj = rec + (size_t)d * 8 + q * 2;
            hi_.v = pi[0]; mi_.v = pi[1];
            hj_.v = pj[0]; mj_.v = pj[1];
        } else {
            const uint4* pi = (const uint4*)(x + (size_t)s * DD + q * 8);
            const uint4* pj = (const uint4*)(x + (size_t)d * DD + q * 8);
            hi_.v = pi[0]; mi_.v = pi[1];
            hj_.v = pj[0]; mj_.v = pj[1];
        }
    };
    // decode one packed side -> 8 fp32 x + bf16 log A-frag (r10-validated)
    auto decode = [&](const Q& h, const Q& m, float* xv, bf16x8& lfrag) {
        #pragma unroll
        for (int p = 0; p < 4; ++p) {
            float lo = __builtin_bit_cast(float, h.u[p] << 16);
            float hi = __builtin_bit_cast(float, h.u[p] & 0xffff0000u);
            unsigned xb = (p < 2) ? m.u[0] : m.u[1];
            float m0 = ubyte(xb, (2 * p) & 3);
            float m1 = ubyte(xb, (2 * p + 1) & 3);
            xv[2 * p]     = fmaf(lo * MSC, m0, lo);
            xv[2 * p + 1] = fmaf(hi * MSC, m1, hi);
        }
        U8 L;
        #pragma unroll
        for (int p = 0; p < 4; ++p) {
            unsigned lb = (p < 2) ? m.u[2] : m.u[3];
            float l0 = fmaf(ubyte(lb, (2 * p) & 3),     LXIV, LXLO);
            float l1 = fmaf(ubyte(lb, (2 * p + 1) & 3), LXIV, LXLO);
            L.u[p] = pk_rne(l0, l1);
        }
        lfrag = L.v;
    };

    auto compute = [&](int tc, const Q& hI, const Q& mI, const Q& hJ, const Q& mJ) {
        float xiv[8], xjv[8];
        bf16x8 aLi, aLj;
        if constexpr (PACK) {
            decode(hI, mI, xiv, aLi);
            decode(hJ, mJ, xjv, aLj);
        } else {
            #pragma unroll
            for (int p = 0; p < 4; ++p) { xiv[p] = hI.f[p]; xiv[4 + p] = mI.f[p]; }
            #pragma unroll
            for (int p = 0; p < 4; ++p) { xjv[p] = hJ.f[p]; xjv[4 + p] = mJ.f[p]; }
            U8 ti, tj;
            #pragma unroll
            for (int p = 0; p < 4; ++p) {
                ti.u[p] = pk_rne(__logf(xiv[2*p] + EPSF), __logf(xiv[2*p+1] + EPSF));
                tj.u[p] = pk_rne(__logf(xjv[2*p] + EPSF), __logf(xjv[2*p+1] + EPSF));
            }
            aLi = ti.v; aLj = tj.v;
        }
        // -lxj: bf16 sign flip on the A side (replaces a WLn weight set)
        U8 nj; nj.v = aLj;
        #pragma unroll
        for (int p = 0; p < 4; ++p) nj.u[p] ^= 0x80008000u;

        U8 R, Rl, Aa, Dd;
        #pragma unroll
        for (int p = 0; p < 4; ++p) {
            float a0 = xiv[2*p], a1 = xiv[2*p+1];
            float c0 = xjv[2*p], c1 = xjv[2*p+1];
            float r0 = a0 * __builtin_amdgcn_rcpf(c0 + EPSF);
            float r1 = a1 * __builtin_amdgcn_rcpf(c1 + EPSF);
            float d0 = fabsf(a0 - c0), d1 = fabsf(a1 - c1);
            float g0 = d0 * __builtin_amdgcn_rcpf(fmaxf(a0, c0) + EPSF);
            float g1 = d1 * __builtin_amdgcn_rcpf(fmaxf(a1, c1) + EPSF);
            R.u[p]  = pk_tr(r0, r1);
            Rl.u[p] = pk_tr(r0 - hi_f32(r0), r1 - hi_f32(r1));
            Aa.u[p] = pk_tr(d0, d1);
            Dd.u[p] = pk_tr(g0, g1);
        }

        // opaque offset: stops LICM hoisting weight ds_reads into registers
        int off = lane;
        asm volatile("" : "+v"(off));
        auto ldfrag = [&](int s, int nt) {
            U8 w; w.q4 = sW[(s * 4 + nt) * 64 + off];
            return w.v;
        };

        f32x4 acc[4];
        #pragma unroll
        for (int nt = 0; nt < 4; ++nt) {
            acc[nt][0] = b1v[nt]; acc[nt][1] = b1v[nt];
            acc[nt][2] = b1v[nt]; acc[nt][3] = b1v[nt];
        }
        #pragma unroll
        for (int nt = 0; nt < 4; ++nt) {
            bf16x8 fW0h = ldfrag(0, nt);
            bf16x8 fW0l = ldfrag(1, nt);
            bf16x8 fWL  = ldfrag(2, nt);
            bf16x8 fWA  = ldfrag(3, nt);
            bf16x8 fWD  = ldfrag(4, nt);
            acc[nt] = __builtin_amdgcn_mfma_f32_16x16x32_bf16(R.v,  fW0h, acc[nt], 0, 0, 0);
            acc[nt] = __builtin_amdgcn_mfma_f32_16x16x32_bf16(Rl.v, fW0h, acc[nt], 0, 0, 0);
            acc[nt] = __builtin_amdgcn_mfma_f32_16x16x32_bf16(R.v,  fW0l, acc[nt], 0, 0, 0);
            acc[nt] = __builtin_amdgcn_mfma_f32_16x16x32_bf16(aLi,  fWL,  acc[nt], 0, 0, 0);
            acc[nt] = __builtin_amdgcn_mfma_f32_16x16x32_bf16(nj.v, fWL,  acc[nt], 0, 0, 0);
            acc[nt] = __builtin_amdgcn_mfma_f32_16x16x32_bf16(Aa.v, fWA,  acc[nt], 0, 0, 0);
            acc[nt] = __builtin_amdgcn_mfma_f32_16x16x32_bf16(Dd.v, fWD,  acc[nt], 0, 0, 0);
        }

        float p[4];
        #pragma unroll
        for (int r = 0; r < 4; ++r) {
            float pp = 0.f;
            #pragma unroll
            for (int nt = 0; nt < 4; ++nt)
                pp = fmaf(fmaxf(acc[nt][r], 0.f), w2v[nt], pp);
            pp += __shfl_xor(pp, 1);
            pp += __shfl_xor(pp, 2);
            pp += __shfl_xor(pp, 4);
            pp += __shfl_xor(pp, 8);
            p[r] = pp;
        }
        if (c < 4) {
            const int e = (tc << 4) + q * 4 + c;
            if (e < E) {
                float v = (c == 0) ? p[0] : (c == 1) ? p[1] : (c == 2) ? p[2] : p[3];
                out[e] = v + b2s;
            }
        }
    };

    // ---- depth-1 pipeline: idx 2 ahead, gathers 1 ahead ----
    Q hiC, miC, hjC, mjC;
    int srcN, dstN;
    { int s, d; ldidx(t, s, d); gather(s, d, hiC, miC, hjC, mjC); }
    ldidx(t + nwv, srcN, dstN);

    for (; t < ntiles; t += nwv) {
        Q hiN, miN, hjN, mjN;
        gather(srcN, dstN, hiN, miN, hjN, mjN);       // tile t+nwv
        int srcN2, dstN2;
        ldidx(t + 2 * nwv, srcN2, dstN2);

        compute(t, hiC, miC, hjC, mjC);

        hiC = hiN; miC = miN; hjC = hjN; mjC = mjN;
        srcN = srcN2; dstN = dstN2;
    }
}

extern "C" void kernel_launch(void* const* d_in, const int* in_sizes, int n_in,
                              void* d_out, int out_size, void* d_ws, size_t ws_size,
                              hipStream_t stream)
{
    const float* x   = (const float*)d_in[0];
    const int*   ei  = (const int*)  d_in[1];
    const float* W1  = (const float*)d_in[2];
    const float* b1  = (const float*)d_in[3];
    const float* W2  = (const float*)d_in[4];
    const float* b2  = (const float*)d_in[5];
    float* out = (float*)d_out;

    const int E  = out_size;       // 1,000,000
    const int Nd = in_sizes[0];    // N*D = 3,200,000
    uint4* rec = (uint4*)d_ws;     // N * 128 bytes = Nd * 4 bytes

    const bool pack = ws_size >= (size_t)Nd * 4 && (Nd % 8) == 0;
    if (pack) {
        const int nchunk = Nd / 8;
        prep_pack<<<(nchunk + 255) / 256, 256, 0, stream>>>(x, rec, nchunk);
        edge_bias_mfma<1><<<2048, 256, 0, stream>>>(x, ei, W1, b1, W2, b2, rec, out, E);
    } else {
        edge_bias_mfma<0><<<2048, 256, 0, stream>>>(x, ei, W1, b1, W2, b2, rec, out, E);
    }
}